// Round 9
// baseline (463.834 us; speedup 1.0000x reference)
//
#include <hip/hip_runtime.h>
#include <hip/hip_bf16.h>
#include <math.h>

// ---------------- problem constants ----------------
#define B_ROWS 1024
#define EMB    512
#define NCLS   100000
#define SCALE_ 64.0f
// margin = 0.5
#define COS_M 0.8775825618903728f
#define SIN_M 0.479425538604203f
#define TH_C  (-0.8775825618903728f)
#define MM_C  0.2397127693021015f

// ---------------- fallback GEMM tiling (128^2, BK=32) ----------------
#define BM 128
#define BN 128
#define BK 32
#define NTILES 782   // ceil(100000/128)
#define KCHUNKS 16   // 512/32

// ---------------- fast GEMM: 128^2, BK=64, double-buffered (1 barrier/chunk) ----
#define BK2   64
#define KCH2  8      // 512/64

typedef __attribute__((ext_vector_type(8))) short bf16x8;   // 8 bf16 = 4 VGPRs
typedef __attribute__((ext_vector_type(4))) short s16x4;
typedef __attribute__((ext_vector_type(4))) float f32x4;

typedef __attribute__((address_space(1))) const unsigned int GLP;
typedef __attribute__((address_space(3))) unsigned int LDP;

__device__ __forceinline__ float bf2f(short u) {
  unsigned int x = ((unsigned int)(unsigned short)u) << 16;
  return __builtin_bit_cast(float, x);
}
__device__ __forceinline__ short f2bf(float f) {   // RNE fp32 -> bf16
  unsigned int u = __builtin_bit_cast(unsigned int, f);
  u += 0x7FFF + ((u >> 16) & 1);
  return (short)(u >> 16);
}

// async global->LDS, 16B/lane; LDS dest = wave-uniform base, lane i lands at base + i*16
__device__ __forceinline__ void load16(const void* g, void* l) {
  __builtin_amdgcn_global_load_lds((GLP*)g, (LDP*)l, 16, 0, 0);
}

#define MFMA16 __builtin_amdgcn_mfma_f32_16x16x32_bf16

// ---------------- setup: zero accums, detect label width AND input dtype ----------------
__global__ void setup_kernel(const void* __restrict__ emb, const int* __restrict__ labels,
                             float* __restrict__ row_sum, float* __restrict__ accum,
                             int* __restrict__ flag, int* __restrict__ dflag) {
  const int t = threadIdx.x;           // 512 threads
  row_sum[t] = 0.f;
  row_sum[t + 512] = 0.f;
  if (t == 0) *accum = 0.f;

  // ---- input dtype probe (wave 0): ssq of emb row 0 read AS bf16.
  if (t < 64) {
    bf16x8 v = *(const bf16x8*)((const short*)emb + t * 8);
    float s = 0.f;
    #pragma unroll
    for (int j = 0; j < 8; ++j) { float f = bf2f(v[j]); s += f * f; }
    #pragma unroll
    for (int off = 1; off < 64; off <<= 1) s += __shfl_xor(s, off);
    if (t == 0) *dflag = (s < 1e8f) ? 1 : 0;       // NaN/inf compare false -> fp32
  }

  // ---- label width probe: high words if int64 are all zero
  int v = labels[2 * t + 1];
  #pragma unroll
  for (int off = 1; off < 64; off <<= 1) v |= __shfl_xor(v, off);
  __shared__ int red[8];
  if ((t & 63) == 0) red[t >> 6] = v;
  __syncthreads();
  if (t == 0) {
    int o = 0;
    #pragma unroll
    for (int i = 0; i < 8; ++i) o |= red[i];
    *flag = (o == 0) ? 1 : 0;          // 1 => int64 labels (read low word at 2*r)
  }
}

// ---------------- inverse L2 norms + (optional) normalized-bf16 write-back ----------------
// v4 (proven round 6): 16 lanes/row, 2 rows/thread (16 outstanding loads),
// non-temporal fp32 reads (dead after this pass; keep L3 for the Wn stream).
__global__ __launch_bounds__(256) void normconv_kernel(
    const void* __restrict__ emb, const void* __restrict__ wgt,
    const int* __restrict__ dflag,
    float* __restrict__ inv_e, float* __restrict__ inv_w,
    short* __restrict__ An, short* __restrict__ Wn, const int do_conv) {
  const int sub  = threadIdx.x & 15;       // lane within row-group
  const int rloc = threadIdx.x >> 4;       // 0..15
  const int isbf16 = *dflag;

  const float* pf[2];
  const short* pb[2];
  float* dst[2];
  short* out[2];
  bool   ok[2];
  #pragma unroll
  for (int h = 0; h < 2; ++h) {
    const int row = blockIdx.x * 32 + h * 16 + rloc;
    int r;
    const void* base;
    if (row < B_ROWS) {                      // blocks 0..31 are pure-emb (1024 = 32*32)
      r = row; base = emb; dst[h] = inv_e + row; out[h] = An + (size_t)row * EMB; ok[h] = true;
    } else {
      r = row - B_ROWS;
      ok[h] = (r < NCLS);
      if (r >= NCLS) r = NCLS - 1;           // clamp: safe load, stores guarded
      base = wgt; dst[h] = inv_w + r; out[h] = Wn + (size_t)r * EMB;
    }
    pf[h] = (const float*)base + (size_t)r * EMB;
    pb[h] = (const short*)base + (size_t)r * EMB;
  }

  if (!isbf16) {
    f32x4 v[2][8];
    #pragma unroll
    for (int j = 0; j < 8; ++j) {           // interleave the two rows' streams
      v[0][j] = __builtin_nontemporal_load((const f32x4*)(pf[0] + j * 64 + sub * 4));
      v[1][j] = __builtin_nontemporal_load((const f32x4*)(pf[1] + j * 64 + sub * 4));
    }
    #pragma unroll
    for (int h = 0; h < 2; ++h) {
      float s = 0.f;
      #pragma unroll
      for (int j = 0; j < 8; ++j)
        #pragma unroll
        for (int t = 0; t < 4; ++t) s += v[h][j][t] * v[h][j][t];
      #pragma unroll
      for (int off = 1; off < 16; off <<= 1) s += __shfl_xor(s, off);
      const float inv = 1.f / fmaxf(sqrtf(s), 1e-12f);
      if (ok[h]) {
        if (sub == 0) *dst[h] = inv;
        if (do_conv) {
          #pragma unroll
          for (int j = 0; j < 8; ++j) {
            s16x4 o;
            #pragma unroll
            for (int t = 0; t < 4; ++t) o[t] = f2bf(v[h][j][t] * inv);
            *(s16x4*)(out[h] + j * 64 + sub * 4) = o;
          }
        }
      }
    }
  } else {
    bf16x8 w[2][4];
    #pragma unroll
    for (int j = 0; j < 4; ++j) {
      w[0][j] = *(const bf16x8*)(pb[0] + j * 128 + sub * 8);
      w[1][j] = *(const bf16x8*)(pb[1] + j * 128 + sub * 8);
    }
    #pragma unroll
    for (int h = 0; h < 2; ++h) {
      float s = 0.f;
      #pragma unroll
      for (int j = 0; j < 4; ++j)
        #pragma unroll
        for (int t = 0; t < 8; ++t) { float f = bf2f(w[h][j][t]); s += f * f; }
      #pragma unroll
      for (int off = 1; off < 16; off <<= 1) s += __shfl_xor(s, off);
      const float inv = 1.f / fmaxf(sqrtf(s), 1e-12f);
      if (ok[h]) {
        if (sub == 0) *dst[h] = inv;
        if (do_conv) {
          #pragma unroll
          for (int j = 0; j < 4; ++j) {
            bf16x8 o;
            #pragma unroll
            for (int t = 0; t < 8; ++t) o[t] = f2bf(bf2f(w[h][j][t]) * inv);
            *(bf16x8*)(out[h] + j * 128 + sub * 8) = o;
          }
        }
      }
    }
  }
}

// ---------------- FAST PATH: 128^2 BK=64 double-buffered NT-GEMM ----------------
// Round-7 kernel + T3 "minimum 2-phase": stage(t+1) into buf^1 BEFORE compute of buf,
// ONE __syncthreads per chunk (its vmcnt(0) drain lands the prefetch, latency hidden
// under ds_read+MFMA). Read-overwrite safe: reads of buf^1 completed before the
// previous barrier. XCD-grouped mapping; XOR swizzle phys_slot = logical ^ (row&7).
__global__ __launch_bounds__(256, 2) void arc_gemm_fast(
    const short* __restrict__ A, const short* __restrict__ W,
    const int* __restrict__ labels, const int* __restrict__ flag,
    float* __restrict__ row_sum, float* __restrict__ lablogit) {
  // XCD-aware decode: HW assigns flat bid round-robin (XCD = bid & 7).
  const int bid = blockIdx.x;
  const int k   = bid & 7;
  const int j   = bid >> 3;              // 0..783
  const int ytile = (j >> 3) * 8 + k;    // N-panel
  const int xtile = j & 7;               // M-tile
  if (ytile >= NTILES) return;

  __shared__ short As[2][BM * BK2];  // 2 x 16 KB, [row][slot] phys, row stride 128 B
  __shared__ short Bs[2][BM * BK2];  // 2 x 16 KB
  __shared__ int   sh_lab[BM];
  __shared__ float sh_sum[BM][2];

  const int tid  = threadIdx.x;
  const int wave = tid >> 6;
  const int lane = tid & 63;
  const int wy = wave >> 1;         // 2x2 wave grid, each wave 64x64
  const int wx = wave & 1;
  const int lr = lane & 15;
  const int lk = lane >> 4;
  const int mBase = xtile * BM;
  const int nBase = ytile * BN;

  // staging: each gload_lds covers 8 rows x 128 B; lane -> row_in=lane>>3, phys=lane&7.
  // source fetches the logical slot that belongs at phys:  sslot = (lane&7) ^ ((lane>>3)&7).
  const int srow8 = lane >> 3;                       // row within 8-row stripe
  const int sslot = (lane & 7) ^ (srow8 & 7);

  f32x4 zero = {0.f, 0.f, 0.f, 0.f};
  f32x4 acc[4][4];
  #pragma unroll
  for (int i = 0; i < 4; ++i)
    #pragma unroll
    for (int jj = 0; jj < 4; ++jj) acc[i][jj] = zero;

  const char* Ab = (const char*)A;   // bf16 row stride 1024 B
  const char* Wb = (const char*)W;

  auto stage = [&](int kc, int p) {
    const size_t koff = (size_t)kc * 128 + sslot * 16;
    #pragma unroll
    for (int it = 0; it < 4; ++it) {
      const int i = wave + it * 4;                  // stage-instr id 0..15 (8 rows each)
      const int ar = mBase + i * 8 + srow8;         // always < 1024
      load16(Ab + (size_t)ar * 1024 + koff, (char*)As[p] + (size_t)i * 1024);
      int br = nBase + i * 8 + srow8;
      if (br >= NCLS) br = NCLS - 1;                // clamp; masked in epilogue
      load16(Wb + (size_t)br * 1024 + koff, (char*)Bs[p] + (size_t)i * 1024);
    }
  };

  // ---- prologue: tile 0 into buf 0 ----
  stage(0, 0);
  __syncthreads();                                  // drains vmcnt -> tile 0 landed

  for (int kc = 0; kc < KCH2; ++kc) {
    const int cur = kc & 1;
    if (kc < KCH2 - 1) stage(kc + 1, cur ^ 1);      // prefetch next tile (latency hidden)

    bf16x8 af[2][4], bfr[2][4];
    #pragma unroll
    for (int mi = 0; mi < 4; ++mi) {
      const int ra = wy * 64 + mi * 16 + lr;
      af[0][mi] = *(const bf16x8*)(&As[cur][0] + ra * BK2 + ((lk       ^ (ra & 7)) * 8));
      af[1][mi] = *(const bf16x8*)(&As[cur][0] + ra * BK2 + (((4 | lk) ^ (ra & 7)) * 8));
    }
    #pragma unroll
    for (int ni = 0; ni < 4; ++ni) {
      const int rb = wx * 64 + ni * 16 + lr;
      bfr[0][ni] = *(const bf16x8*)(&Bs[cur][0] + rb * BK2 + ((lk       ^ (rb & 7)) * 8));
      bfr[1][ni] = *(const bf16x8*)(&Bs[cur][0] + rb * BK2 + (((4 | lk) ^ (rb & 7)) * 8));
    }
    #pragma unroll
    for (int mi = 0; mi < 4; ++mi)
      #pragma unroll
      for (int ni = 0; ni < 4; ++ni) {
        acc[mi][ni] = MFMA16(af[0][mi], bfr[0][ni], acc[mi][ni], 0, 0, 0);
        acc[mi][ni] = MFMA16(af[1][mi], bfr[1][ni], acc[mi][ni], 0, 0, 0);
      }

    __syncthreads();   // vmcnt(0): prefetch landed; all waves' reads of cur done
  }

  // ---- epilogue (cos = accumulator directly; inputs pre-normalized) ----
  if (tid < BM) {
    const int r = mBase + tid;
    const int f = *flag;
    sh_lab[tid] = labels[f ? (size_t)(2 * r) : (size_t)r];
  }
  __syncthreads();

  #pragma unroll
  for (int mi = 0; mi < 4; ++mi) {
    #pragma unroll
    for (int reg = 0; reg < 4; ++reg) {
      const int lrow = wy * 64 + mi * 16 + lk * 4 + reg;   // C/D: row=(lane>>4)*4+reg
      const int grow = mBase + lrow;
      const int lab = sh_lab[lrow];
      float s = 0.f;
      #pragma unroll
      for (int ni = 0; ni < 4; ++ni) {
        const int gcol = nBase + wx * 64 + ni * 16 + lr;   // C/D: col=lane&15
        if (gcol < NCLS) {
          const float cosv = acc[mi][ni][reg];
          float logit;
          if (gcol == lab) {
            const float sine = sqrtf(fmaxf(1.f - cosv * cosv, 0.f));
            float phi = cosv * COS_M - sine * SIN_M;
            phi = (cosv > TH_C) ? phi : (cosv - MM_C);
            logit = SCALE_ * phi;
            lablogit[grow] = logit;                        // unique writer grid-wide
          } else {
            logit = SCALE_ * cosv;
          }
          s += __expf(logit - SCALE_);                     // offset-64 softmax partial
        }
      }
      #pragma unroll
      for (int off = 1; off < 16; off <<= 1) s += __shfl_xor(s, off);
      if (lr == 0) sh_sum[lrow][wx] = s;
    }
  }
  __syncthreads();
  if (tid < BM)
    atomicAdd(&row_sum[mBase + tid], sh_sum[tid][0] + sh_sum[tid][1]);
}

// ---------------- FALLBACK: fused NT-GEMM with in-loop dtype staging (BK=32) ----------------
__global__ __launch_bounds__(256, 3) void arc_gemm(
    const void* __restrict__ A, const void* __restrict__ W,
    const float* __restrict__ inv_e, const float* __restrict__ inv_w,
    const int* __restrict__ labels, const int* __restrict__ flag,
    const int* __restrict__ dflag,
    float* __restrict__ row_sum, float* __restrict__ lablogit) {
  __shared__ short As[BM * BK];
  __shared__ short Bs[BN * BK];
  __shared__ int   sh_lab[BM];
  __shared__ float sh_sum[BM][2];

  const int tid  = threadIdx.x;
  const int wave = tid >> 6;
  const int lane = tid & 63;
  const int wy = wave >> 1;
  const int wx = wave & 1;
  const int lr = lane & 15;
  const int lk = lane >> 4;
  const int mBase = blockIdx.x * BM;
  const int nBase = blockIdx.y * BN;
  const int isbf16 = *dflag;

  const int srow  = lane >> 2;
  const int sbyte = (lane & 3) * 16;

  f32x4 zero = {0.f, 0.f, 0.f, 0.f};
  f32x4 acc[4][4];
  #pragma unroll
  for (int i = 0; i < 4; ++i)
    #pragma unroll
    for (int j = 0; j < 4; ++j) acc[i][j] = zero;

  const char*  Ab = (const char*)A;
  const char*  Wb = (const char*)W;
  const float* Af = (const float*)A;
  const float* Wf = (const float*)W;

  for (int kc = 0; kc < KCHUNKS; ++kc) {
    __syncthreads();
    if (isbf16) {
      const size_t koff = (size_t)kc * 64 + sbyte;
      #pragma unroll
      for (int it = 0; it < 2; ++it) {
        const int c = wave + it * 4;
        const int ar = mBase + c * 16 + srow;
        load16(Ab + (size_t)ar * 1024 + koff, (char*)As + (size_t)c * 1024);
        int br = nBase + c * 16 + srow;
        if (br >= NCLS) br = NCLS - 1;
        load16(Wb + (size_t)br * 1024 + koff, (char*)Bs + (size_t)c * 1024);
      }
    } else {
      #pragma unroll
      for (int p = 0; p < 2; ++p) {
        const int u   = p * 256 + tid;
        const int row = u >> 2;
        const int seg = u & 3;
        const float* ga = Af + ((size_t)(mBase + row) * EMB + kc * 32 + seg * 8);
        f32x4 x = *(const f32x4*)ga;
        f32x4 y = *(const f32x4*)(ga + 4);
        bf16x8 tpack;
        #pragma unroll
        for (int j = 0; j < 4; ++j) { tpack[j] = f2bf(x[j]); tpack[j + 4] = f2bf(y[j]); }
        *(bf16x8*)(As + row * BK + seg * 8) = tpack;
        int br = nBase + row;
        if (br >= NCLS) br = NCLS - 1;
        const float* gb = Wf + ((size_t)br * EMB + kc * 32 + seg * 8);
        x = *(const f32x4*)gb;
        y = *(const f32x4*)(gb + 4);
        #pragma unroll
        for (int j = 0; j < 4; ++j) { tpack[j] = f2bf(x[j]); tpack[j + 4] = f2bf(y[j]); }
        *(bf16x8*)(Bs + row * BK + seg * 8) = tpack;
      }
    }
    __syncthreads();
    bf16x8 af[4], bfr[4];
    #pragma unroll
    for (int mi = 0; mi < 4; ++mi)
      af[mi] = *(const bf16x8*)(As + ((wy * 64 + mi * 16 + lr) * BK + lk * 8));
    #pragma unroll
    for (int ni = 0; ni < 4; ++ni)
      bfr[ni] = *(const bf16x8*)(Bs + ((wx * 64 + ni * 16 + lr) * BK + lk * 8));
    #pragma unroll
    for (int mi = 0; mi < 4; ++mi)
      #pragma unroll
      for (int ni = 0; ni < 4; ++ni)
        acc[mi][ni] = MFMA16(af[mi], bfr[ni], acc[mi][ni], 0, 0, 0);
  }

  __syncthreads();
  if (tid < BM) {
    const int r = mBase + tid;
    const int f = *flag;
    sh_lab[tid] = labels[f ? (size_t)(2 * r) : (size_t)r];
  }
  __syncthreads();

  #pragma unroll
  for (int mi = 0; mi < 4; ++mi) {
    #pragma unroll
    for (int reg = 0; reg < 4; ++reg) {
      const int lrow = wy * 64 + mi * 16 + lk * 4 + reg;
      const int grow = mBase + lrow;
      const float ie = inv_e[grow];
      const int lab = sh_lab[lrow];
      float s = 0.f;
      #pragma unroll
      for (int ni = 0; ni < 4; ++ni) {
        const int gcol = nBase + wx * 64 + ni * 16 + lr;
        if (gcol < NCLS) {
          const float cosv = acc[mi][ni][reg] * ie * inv_w[gcol];
          float logit;
          if (gcol == lab) {
            const float sine = sqrtf(fmaxf(1.f - cosv * cosv, 0.f));
            float phi = cosv * COS_M - sine * SIN_M;
            phi = (cosv > TH_C) ? phi : (cosv - MM_C);
            logit = SCALE_ * phi;
            lablogit[grow] = logit;
          } else {
            logit = SCALE_ * cosv;
          }
          s += __expf(logit - SCALE_);
        }
      }
      #pragma unroll
      for (int off = 1; off < 16; off <<= 1) s += __shfl_xor(s, off);
      if (lr == 0) sh_sum[lrow][wx] = s;
    }
  }
  __syncthreads();
  if (tid < BM)
    atomicAdd(&row_sum[mBase + tid], sh_sum[tid][0] + sh_sum[tid][1]);
}

// ---------------- fused per-row loss -> mean (single block) ----------------
__global__ __launch_bounds__(512) void loss_kernel(const float* __restrict__ row_sum,
                                                   const float* __restrict__ lablogit,
                                                   float* __restrict__ out) {
  const int t = threadIdx.x;
  float loss = 0.f;
  #pragma unroll
  for (int i = 0; i < 2; ++i) {
    const int r = t + i * 512;
    loss += SCALE_ + logf(row_sum[r]) - lablogit[r];
  }
  #pragma unroll
  for (int off = 1; off < 64; off <<= 1) loss += __shfl_xor(loss, off);
  __shared__ float rs[8];
  if ((t & 63) == 0) rs[t >> 6] = loss;
  __syncthreads();
  if (t == 0) {
    float s = 0.f;
    #pragma unroll
    for (int i = 0; i < 8; ++i) s += rs[i];
    out[0] = s * (1.0f / 1024.0f);   // reference output is float32
  }
}

// ---------------- launch ----------------
extern "C" void kernel_launch(void* const* d_in, const int* in_sizes, int n_in,
                              void* d_out, int out_size, void* d_ws, size_t ws_size,
                              hipStream_t stream) {
  const void* emb   = d_in[0];          // [1024][512]  bf16 or fp32 (auto-detected)
  const void* wgt   = d_in[1];          // [100000][512]
  const int* labels = (const int*)d_in[2];   // int32 or int64 (auto-detected)
  float* out = (float*)d_out;

  const int NORM_BLOCKS = (B_ROWS + NCLS + 31) / 32;   // 32 rows/block, 2 rows/thread

  // fast-path workspace: pre-normalized bf16 copies of W and A
  const size_t WN_SHORTS = (size_t)NCLS * EMB;        // 51,200,000
  const size_t AN_SHORTS = (size_t)B_ROWS * EMB;      // 524,288
  const size_t FAST_NEED = (WN_SHORTS + AN_SHORTS) * 2 + 103075u * 4;  // ~103.9 MB

  if (ws_size >= FAST_NEED) {
    short* Wn = (short*)d_ws;
    short* An = Wn + WN_SHORTS;
    float* tail     = (float*)(An + AN_SHORTS);
    float* inv_e    = tail;               // 1024 (fallback parity)
    float* inv_w    = tail + 1024;        // 100000
    float* lablogit = tail + 101024;      // 1024
    float* row_sum  = tail + 102048;      // 1024
    float* accum    = tail + 103072;      // 1
    int*   flag     = (int*)(tail + 103073);
    int*   dflag    = (int*)(tail + 103074);

    setup_kernel<<<1, 512, 0, stream>>>(emb, labels, row_sum, accum, flag, dflag);
    normconv_kernel<<<NORM_BLOCKS, 256, 0, stream>>>(
        emb, wgt, dflag, inv_e, inv_w, An, Wn, 1);
    // 8 XCDs x 784 blocks each (ceil(782/8)*8 y-groups x 8 x-tiles); 16 no-op blocks
    arc_gemm_fast<<<8 * 784, 256, 0, stream>>>(An, Wn, labels, flag, row_sum, lablogit);
    loss_kernel<<<1, 512, 0, stream>>>(row_sum, lablogit, out);
  } else {
    float* ws       = (float*)d_ws;
    float* inv_e    = ws;                 // 1024
    float* inv_w    = ws + 1024;          // 100000
    float* lablogit = ws + 101024;        // 1024
    float* row_sum  = ws + 102048;        // 1024
    float* accum    = ws + 103072;        // 1
    int*   flag     = (int*)(ws + 103073);
    int*   dflag    = (int*)(ws + 103074);

    setup_kernel<<<1, 512, 0, stream>>>(emb, labels, row_sum, accum, flag, dflag);
    normconv_kernel<<<NORM_BLOCKS, 256, 0, stream>>>(
        emb, wgt, dflag, inv_e, inv_w, (short*)inv_e, (short*)inv_e, 0);
    dim3 grid(8, NTILES);
    arc_gemm<<<grid, 256, 0, stream>>>(emb, wgt, inv_e, inv_w, labels, flag, dflag, row_sum, lablogit);
    loss_kernel<<<1, 512, 0, stream>>>(row_sum, lablogit, out);
  }
}

// Round 10
// 426.602 us; speedup vs baseline: 1.0873x; 1.0873x over previous
//
#include <hip/hip_runtime.h>
#include <hip/hip_bf16.h>
#include <math.h>

// ---------------- problem constants ----------------
#define B_ROWS 1024
#define EMB    512
#define NCLS   100000
#define SCALE_ 64.0f
// margin = 0.5
#define COS_M 0.8775825618903728f
#define SIN_M 0.479425538604203f
#define TH_C  (-0.8775825618903728f)
#define MM_C  0.2397127693021015f

// ---------------- fallback GEMM tiling (128^2, BK=32) ----------------
#define BM 128
#define BN 128
#define BK 32
#define NTILES 782   // ceil(100000/128)
#define KCHUNKS 16   // 512/32

// ---------------- fast GEMM: 128^2, BK=64, single-buffered (round-7 proven) ----
#define BK2   64
#define KCH2  8      // 512/64

typedef __attribute__((ext_vector_type(8))) short bf16x8;   // 8 bf16 = 4 VGPRs
typedef __attribute__((ext_vector_type(4))) short s16x4;
typedef __attribute__((ext_vector_type(4))) float f32x4;

typedef __attribute__((address_space(1))) const unsigned int GLP;
typedef __attribute__((address_space(3))) unsigned int LDP;

__device__ __forceinline__ float bf2f(short u) {
  unsigned int x = ((unsigned int)(unsigned short)u) << 16;
  return __builtin_bit_cast(float, x);
}
__device__ __forceinline__ short f2bf(float f) {   // RNE fp32 -> bf16
  unsigned int u = __builtin_bit_cast(unsigned int, f);
  u += 0x7FFF + ((u >> 16) & 1);
  return (short)(u >> 16);
}

// async global->LDS, 16B/lane; LDS dest = wave-uniform base, lane i lands at base + i*16
__device__ __forceinline__ void load16(const void* g, void* l) {
  __builtin_amdgcn_global_load_lds((GLP*)g, (LDP*)l, 16, 0, 0);
}

#define MFMA16 __builtin_amdgcn_mfma_f32_16x16x32_bf16

// ---------------- setup: zero accums, detect label width AND input dtype ----------------
__global__ void setup_kernel(const void* __restrict__ emb, const int* __restrict__ labels,
                             float* __restrict__ row_sum, float* __restrict__ accum,
                             int* __restrict__ flag, int* __restrict__ dflag) {
  const int t = threadIdx.x;           // 512 threads
  row_sum[t] = 0.f;
  row_sum[t + 512] = 0.f;
  if (t == 0) *accum = 0.f;

  // ---- input dtype probe (wave 0): ssq of emb row 0 read AS bf16.
  if (t < 64) {
    bf16x8 v = *(const bf16x8*)((const short*)emb + t * 8);
    float s = 0.f;
    #pragma unroll
    for (int j = 0; j < 8; ++j) { float f = bf2f(v[j]); s += f * f; }
    #pragma unroll
    for (int off = 1; off < 64; off <<= 1) s += __shfl_xor(s, off);
    if (t == 0) *dflag = (s < 1e8f) ? 1 : 0;       // NaN/inf compare false -> fp32
  }

  // ---- label width probe: high words if int64 are all zero
  int v = labels[2 * t + 1];
  #pragma unroll
  for (int off = 1; off < 64; off <<= 1) v |= __shfl_xor(v, off);
  __shared__ int red[8];
  if ((t & 63) == 0) red[t >> 6] = v;
  __syncthreads();
  if (t == 0) {
    int o = 0;
    #pragma unroll
    for (int i = 0; i < 8; ++i) o |= red[i];
    *flag = (o == 0) ? 1 : 0;          // 1 => int64 labels (read low word at 2*r)
  }
}

// ---------------- inverse L2 norms + (optional) normalized-bf16 write-back ----------------
// v4 (proven round 6): 16 lanes/row, 2 rows/thread (16 outstanding loads),
// non-temporal fp32 reads (dead after this pass; keep L3 for the Wn stream).
__global__ __launch_bounds__(256) void normconv_kernel(
    const void* __restrict__ emb, const void* __restrict__ wgt,
    const int* __restrict__ dflag,
    float* __restrict__ inv_e, float* __restrict__ inv_w,
    short* __restrict__ An, short* __restrict__ Wn, const int do_conv) {
  const int sub  = threadIdx.x & 15;       // lane within row-group
  const int rloc = threadIdx.x >> 4;       // 0..15
  const int isbf16 = *dflag;

  const float* pf[2];
  const short* pb[2];
  float* dst[2];
  short* out[2];
  bool   ok[2];
  #pragma unroll
  for (int h = 0; h < 2; ++h) {
    const int row = blockIdx.x * 32 + h * 16 + rloc;
    int r;
    const void* base;
    if (row < B_ROWS) {                      // blocks 0..31 are pure-emb (1024 = 32*32)
      r = row; base = emb; dst[h] = inv_e + row; out[h] = An + (size_t)row * EMB; ok[h] = true;
    } else {
      r = row - B_ROWS;
      ok[h] = (r < NCLS);
      if (r >= NCLS) r = NCLS - 1;           // clamp: safe load, stores guarded
      base = wgt; dst[h] = inv_w + r; out[h] = Wn + (size_t)r * EMB;
    }
    pf[h] = (const float*)base + (size_t)r * EMB;
    pb[h] = (const short*)base + (size_t)r * EMB;
  }

  if (!isbf16) {
    f32x4 v[2][8];
    #pragma unroll
    for (int j = 0; j < 8; ++j) {           // interleave the two rows' streams
      v[0][j] = __builtin_nontemporal_load((const f32x4*)(pf[0] + j * 64 + sub * 4));
      v[1][j] = __builtin_nontemporal_load((const f32x4*)(pf[1] + j * 64 + sub * 4));
    }
    #pragma unroll
    for (int h = 0; h < 2; ++h) {
      float s = 0.f;
      #pragma unroll
      for (int j = 0; j < 8; ++j)
        #pragma unroll
        for (int t = 0; t < 4; ++t) s += v[h][j][t] * v[h][j][t];
      #pragma unroll
      for (int off = 1; off < 16; off <<= 1) s += __shfl_xor(s, off);
      const float inv = 1.f / fmaxf(sqrtf(s), 1e-12f);
      if (ok[h]) {
        if (sub == 0) *dst[h] = inv;
        if (do_conv) {
          #pragma unroll
          for (int j = 0; j < 8; ++j) {
            s16x4 o;
            #pragma unroll
            for (int t = 0; t < 4; ++t) o[t] = f2bf(v[h][j][t] * inv);
            *(s16x4*)(out[h] + j * 64 + sub * 4) = o;
          }
        }
      }
    }
  } else {
    bf16x8 w[2][4];
    #pragma unroll
    for (int j = 0; j < 4; ++j) {
      w[0][j] = *(const bf16x8*)(pb[0] + j * 128 + sub * 8);
      w[1][j] = *(const bf16x8*)(pb[1] + j * 128 + sub * 8);
    }
    #pragma unroll
    for (int h = 0; h < 2; ++h) {
      float s = 0.f;
      #pragma unroll
      for (int j = 0; j < 4; ++j)
        #pragma unroll
        for (int t = 0; t < 8; ++t) { float f = bf2f(w[h][j][t]); s += f * f; }
      #pragma unroll
      for (int off = 1; off < 16; off <<= 1) s += __shfl_xor(s, off);
      const float inv = 1.f / fmaxf(sqrtf(s), 1e-12f);
      if (ok[h]) {
        if (sub == 0) *dst[h] = inv;
        if (do_conv) {
          #pragma unroll
          for (int j = 0; j < 4; ++j) {
            bf16x8 o;
            #pragma unroll
            for (int t = 0; t < 8; ++t) o[t] = f2bf(bf2f(w[h][j][t]) * inv);
            *(bf16x8*)(out[h] + j * 128 + sub * 8) = o;
          }
        }
      }
    }
  }
}

// ---------------- FAST PATH: 128^2 BK=64 NT-GEMM (round-7 proven) ----------------
// ONE change vs round 7: __launch_bounds__(256, 4) -> 4 blocks/CU (137 KB LDS fits;
// 72 VGPR fits 4 waves/SIMD). Round 9 proved occupancy, not intra-block pipelining,
// is the binding resource: MfmaUtil tracked wave count, dbuf prefetch added nothing.
// XCD-grouped mapping; XOR swizzle phys_slot = logical ^ (row&7) via pre-swizzled source.
__global__ __launch_bounds__(256, 4) void arc_gemm_fast(
    const short* __restrict__ A, const short* __restrict__ W,
    const int* __restrict__ labels, const int* __restrict__ flag,
    float* __restrict__ row_sum, float* __restrict__ lablogit) {
  // XCD-aware decode: HW assigns flat bid round-robin (XCD = bid & 7).
  const int bid = blockIdx.x;
  const int k   = bid & 7;
  const int j   = bid >> 3;              // 0..783
  const int ytile = (j >> 3) * 8 + k;    // N-panel
  const int xtile = j & 7;               // M-tile
  if (ytile >= NTILES) return;

  __shared__ short As[BM * BK2];    // 16 KB, [row][slot] phys, row stride 128 B
  __shared__ short Bs[BN * BK2];    // 16 KB
  __shared__ int   sh_lab[BM];
  __shared__ float sh_sum[BM][2];

  const int tid  = threadIdx.x;
  const int wave = tid >> 6;
  const int lane = tid & 63;
  const int wy = wave >> 1;         // 2x2 wave grid, each wave 64x64
  const int wx = wave & 1;
  const int lr = lane & 15;
  const int lk = lane >> 4;
  const int mBase = xtile * BM;
  const int nBase = ytile * BN;

  // staging: each gload_lds covers 8 rows x 128 B; lane -> row_in=lane>>3, phys=lane&7.
  // source fetches the logical slot that belongs at phys:  sslot = (lane&7) ^ ((lane>>3)&7).
  const int srow8 = lane >> 3;                       // row within 8-row stripe
  const int sslot = (lane & 7) ^ (srow8 & 7);

  f32x4 zero = {0.f, 0.f, 0.f, 0.f};
  f32x4 acc[4][4];
  #pragma unroll
  for (int i = 0; i < 4; ++i)
    #pragma unroll
    for (int jj = 0; jj < 4; ++jj) acc[i][jj] = zero;

  const char* Ab = (const char*)A;   // bf16 row stride 1024 B
  const char* Wb = (const char*)W;

  for (int kc = 0; kc < KCH2; ++kc) {
    __syncthreads();
    const size_t koff = (size_t)kc * 128 + sslot * 16;
    #pragma unroll
    for (int it = 0; it < 4; ++it) {
      const int i = wave + it * 4;                  // stage-instr id 0..15 (8 rows each)
      const int ar = mBase + i * 8 + srow8;         // always < 1024
      load16(Ab + (size_t)ar * 1024 + koff, (char*)As + (size_t)i * 1024);
      int br = nBase + i * 8 + srow8;
      if (br >= NCLS) br = NCLS - 1;                // clamp; masked in epilogue
      load16(Wb + (size_t)br * 1024 + koff, (char*)Bs + (size_t)i * 1024);
    }
    __syncthreads();                                // drains vmcnt/lgkmcnt before use

    bf16x8 af[2][4], bfr[2][4];
    #pragma unroll
    for (int mi = 0; mi < 4; ++mi) {
      const int ra = wy * 64 + mi * 16 + lr;
      af[0][mi] = *(const bf16x8*)(As + ra * BK2 + ((lk       ^ (ra & 7)) * 8));
      af[1][mi] = *(const bf16x8*)(As + ra * BK2 + (((4 | lk) ^ (ra & 7)) * 8));
    }
    #pragma unroll
    for (int ni = 0; ni < 4; ++ni) {
      const int rb = wx * 64 + ni * 16 + lr;
      bfr[0][ni] = *(const bf16x8*)(Bs + rb * BK2 + ((lk       ^ (rb & 7)) * 8));
      bfr[1][ni] = *(const bf16x8*)(Bs + rb * BK2 + (((4 | lk) ^ (rb & 7)) * 8));
    }
    #pragma unroll
    for (int mi = 0; mi < 4; ++mi)
      #pragma unroll
      for (int ni = 0; ni < 4; ++ni) {
        acc[mi][ni] = MFMA16(af[0][mi], bfr[0][ni], acc[mi][ni], 0, 0, 0);
        acc[mi][ni] = MFMA16(af[1][mi], bfr[1][ni], acc[mi][ni], 0, 0, 0);
      }
  }

  // ---- epilogue (cos = accumulator directly; inputs pre-normalized) ----
  __syncthreads();
  if (tid < BM) {
    const int r = mBase + tid;
    const int f = *flag;
    sh_lab[tid] = labels[f ? (size_t)(2 * r) : (size_t)r];
  }
  __syncthreads();

  #pragma unroll
  for (int mi = 0; mi < 4; ++mi) {
    #pragma unroll
    for (int reg = 0; reg < 4; ++reg) {
      const int lrow = wy * 64 + mi * 16 + lk * 4 + reg;   // C/D: row=(lane>>4)*4+reg
      const int grow = mBase + lrow;
      const int lab = sh_lab[lrow];
      float s = 0.f;
      #pragma unroll
      for (int ni = 0; ni < 4; ++ni) {
        const int gcol = nBase + wx * 64 + ni * 16 + lr;   // C/D: col=lane&15
        if (gcol < NCLS) {
          const float cosv = acc[mi][ni][reg];
          float logit;
          if (gcol == lab) {
            const float sine = sqrtf(fmaxf(1.f - cosv * cosv, 0.f));
            float phi = cosv * COS_M - sine * SIN_M;
            phi = (cosv > TH_C) ? phi : (cosv - MM_C);
            logit = SCALE_ * phi;
            lablogit[grow] = logit;                        // unique writer grid-wide
          } else {
            logit = SCALE_ * cosv;
          }
          s += __expf(logit - SCALE_);                     // offset-64 softmax partial
        }
      }
      #pragma unroll
      for (int off = 1; off < 16; off <<= 1) s += __shfl_xor(s, off);
      if (lr == 0) sh_sum[lrow][wx] = s;
    }
  }
  __syncthreads();
  if (tid < BM)
    atomicAdd(&row_sum[mBase + tid], sh_sum[tid][0] + sh_sum[tid][1]);
}

// ---------------- FALLBACK: fused NT-GEMM with in-loop dtype staging (BK=32) ----------------
__global__ __launch_bounds__(256, 3) void arc_gemm(
    const void* __restrict__ A, const void* __restrict__ W,
    const float* __restrict__ inv_e, const float* __restrict__ inv_w,
    const int* __restrict__ labels, const int* __restrict__ flag,
    const int* __restrict__ dflag,
    float* __restrict__ row_sum, float* __restrict__ lablogit) {
  __shared__ short As[BM * BK];
  __shared__ short Bs[BN * BK];
  __shared__ int   sh_lab[BM];
  __shared__ float sh_sum[BM][2];

  const int tid  = threadIdx.x;
  const int wave = tid >> 6;
  const int lane = tid & 63;
  const int wy = wave >> 1;
  const int wx = wave & 1;
  const int lr = lane & 15;
  const int lk = lane >> 4;
  const int mBase = blockIdx.x * BM;
  const int nBase = blockIdx.y * BN;
  const int isbf16 = *dflag;

  const int srow  = lane >> 2;
  const int sbyte = (lane & 3) * 16;

  f32x4 zero = {0.f, 0.f, 0.f, 0.f};
  f32x4 acc[4][4];
  #pragma unroll
  for (int i = 0; i < 4; ++i)
    #pragma unroll
    for (int j = 0; j < 4; ++j) acc[i][j] = zero;

  const char*  Ab = (const char*)A;
  const char*  Wb = (const char*)W;
  const float* Af = (const float*)A;
  const float* Wf = (const float*)W;

  for (int kc = 0; kc < KCHUNKS; ++kc) {
    __syncthreads();
    if (isbf16) {
      const size_t koff = (size_t)kc * 64 + sbyte;
      #pragma unroll
      for (int it = 0; it < 2; ++it) {
        const int c = wave + it * 4;
        const int ar = mBase + c * 16 + srow;
        load16(Ab + (size_t)ar * 1024 + koff, (char*)As + (size_t)c * 1024);
        int br = nBase + c * 16 + srow;
        if (br >= NCLS) br = NCLS - 1;
        load16(Wb + (size_t)br * 1024 + koff, (char*)Bs + (size_t)c * 1024);
      }
    } else {
      #pragma unroll
      for (int p = 0; p < 2; ++p) {
        const int u   = p * 256 + tid;
        const int row = u >> 2;
        const int seg = u & 3;
        const float* ga = Af + ((size_t)(mBase + row) * EMB + kc * 32 + seg * 8);
        f32x4 x = *(const f32x4*)ga;
        f32x4 y = *(const f32x4*)(ga + 4);
        bf16x8 tpack;
        #pragma unroll
        for (int j = 0; j < 4; ++j) { tpack[j] = f2bf(x[j]); tpack[j + 4] = f2bf(y[j]); }
        *(bf16x8*)(As + row * BK + seg * 8) = tpack;
        int br = nBase + row;
        if (br >= NCLS) br = NCLS - 1;
        const float* gb = Wf + ((size_t)br * EMB + kc * 32 + seg * 8);
        x = *(const f32x4*)gb;
        y = *(const f32x4*)(gb + 4);
        #pragma unroll
        for (int j = 0; j < 4; ++j) { tpack[j] = f2bf(x[j]); tpack[j + 4] = f2bf(y[j]); }
        *(bf16x8*)(Bs + row * BK + seg * 8) = tpack;
      }
    }
    __syncthreads();
    bf16x8 af[4], bfr[4];
    #pragma unroll
    for (int mi = 0; mi < 4; ++mi)
      af[mi] = *(const bf16x8*)(As + ((wy * 64 + mi * 16 + lr) * BK + lk * 8));
    #pragma unroll
    for (int ni = 0; ni < 4; ++ni)
      bfr[ni] = *(const bf16x8*)(Bs + ((wx * 64 + ni * 16 + lr) * BK + lk * 8));
    #pragma unroll
    for (int mi = 0; mi < 4; ++mi)
      #pragma unroll
      for (int ni = 0; ni < 4; ++ni)
        acc[mi][ni] = MFMA16(af[mi], bfr[ni], acc[mi][ni], 0, 0, 0);
  }

  __syncthreads();
  if (tid < BM) {
    const int r = mBase + tid;
    const int f = *flag;
    sh_lab[tid] = labels[f ? (size_t)(2 * r) : (size_t)r];
  }
  __syncthreads();

  #pragma unroll
  for (int mi = 0; mi < 4; ++mi) {
    #pragma unroll
    for (int reg = 0; reg < 4; ++reg) {
      const int lrow = wy * 64 + mi * 16 + lk * 4 + reg;
      const int grow = mBase + lrow;
      const float ie = inv_e[grow];
      const int lab = sh_lab[lrow];
      float s = 0.f;
      #pragma unroll
      for (int ni = 0; ni < 4; ++ni) {
        const int gcol = nBase + wx * 64 + ni * 16 + lr;
        if (gcol < NCLS) {
          const float cosv = acc[mi][ni][reg] * ie * inv_w[gcol];
          float logit;
          if (gcol == lab) {
            const float sine = sqrtf(fmaxf(1.f - cosv * cosv, 0.f));
            float phi = cosv * COS_M - sine * SIN_M;
            phi = (cosv > TH_C) ? phi : (cosv - MM_C);
            logit = SCALE_ * phi;
            lablogit[grow] = logit;
          } else {
            logit = SCALE_ * cosv;
          }
          s += __expf(logit - SCALE_);
        }
      }
      #pragma unroll
      for (int off = 1; off < 16; off <<= 1) s += __shfl_xor(s, off);
      if (lr == 0) sh_sum[lrow][wx] = s;
    }
  }
  __syncthreads();
  if (tid < BM)
    atomicAdd(&row_sum[mBase + tid], sh_sum[tid][0] + sh_sum[tid][1]);
}

// ---------------- fused per-row loss -> mean (single block) ----------------
__global__ __launch_bounds__(512) void loss_kernel(const float* __restrict__ row_sum,
                                                   const float* __restrict__ lablogit,
                                                   float* __restrict__ out) {
  const int t = threadIdx.x;
  float loss = 0.f;
  #pragma unroll
  for (int i = 0; i < 2; ++i) {
    const int r = t + i * 512;
    loss += SCALE_ + logf(row_sum[r]) - lablogit[r];
  }
  #pragma unroll
  for (int off = 1; off < 64; off <<= 1) loss += __shfl_xor(loss, off);
  __shared__ float rs[8];
  if ((t & 63) == 0) rs[t >> 6] = loss;
  __syncthreads();
  if (t == 0) {
    float s = 0.f;
    #pragma unroll
    for (int i = 0; i < 8; ++i) s += rs[i];
    out[0] = s * (1.0f / 1024.0f);   // reference output is float32
  }
}

// ---------------- launch ----------------
extern "C" void kernel_launch(void* const* d_in, const int* in_sizes, int n_in,
                              void* d_out, int out_size, void* d_ws, size_t ws_size,
                              hipStream_t stream) {
  const void* emb   = d_in[0];          // [1024][512]  bf16 or fp32 (auto-detected)
  const void* wgt   = d_in[1];          // [100000][512]
  const int* labels = (const int*)d_in[2];   // int32 or int64 (auto-detected)
  float* out = (float*)d_out;

  const int NORM_BLOCKS = (B_ROWS + NCLS + 31) / 32;   // 32 rows/block, 2 rows/thread

  // fast-path workspace: pre-normalized bf16 copies of W and A
  const size_t WN_SHORTS = (size_t)NCLS * EMB;        // 51,200,000
  const size_t AN_SHORTS = (size_t)B_ROWS * EMB;      // 524,288
  const size_t FAST_NEED = (WN_SHORTS + AN_SHORTS) * 2 + 103075u * 4;  // ~103.9 MB

  if (ws_size >= FAST_NEED) {
    short* Wn = (short*)d_ws;
    short* An = Wn + WN_SHORTS;
    float* tail     = (float*)(An + AN_SHORTS);
    float* inv_e    = tail;               // 1024 (fallback parity)
    float* inv_w    = tail + 1024;        // 100000
    float* lablogit = tail + 101024;      // 1024
    float* row_sum  = tail + 102048;      // 1024
    float* accum    = tail + 103072;      // 1
    int*   flag     = (int*)(tail + 103073);
    int*   dflag    = (int*)(tail + 103074);

    setup_kernel<<<1, 512, 0, stream>>>(emb, labels, row_sum, accum, flag, dflag);
    normconv_kernel<<<NORM_BLOCKS, 256, 0, stream>>>(
        emb, wgt, dflag, inv_e, inv_w, An, Wn, 1);
    // 8 XCDs x 784 blocks each (ceil(782/8)*8 y-groups x 8 x-tiles); 16 no-op blocks
    arc_gemm_fast<<<8 * 784, 256, 0, stream>>>(An, Wn, labels, flag, row_sum, lablogit);
    loss_kernel<<<1, 512, 0, stream>>>(row_sum, lablogit, out);
  } else {
    float* ws       = (float*)d_ws;
    float* inv_e    = ws;                 // 1024
    float* inv_w    = ws + 1024;          // 100000
    float* lablogit = ws + 101024;        // 1024
    float* row_sum  = ws + 102048;        // 1024
    float* accum    = ws + 103072;        // 1
    int*   flag     = (int*)(ws + 103073);
    int*   dflag    = (int*)(ws + 103074);

    setup_kernel<<<1, 512, 0, stream>>>(emb, labels, row_sum, accum, flag, dflag);
    normconv_kernel<<<NORM_BLOCKS, 256, 0, stream>>>(
        emb, wgt, dflag, inv_e, inv_w, (short*)inv_e, (short*)inv_e, 0);
    dim3 grid(8, NTILES);
    arc_gemm<<<grid, 256, 0, stream>>>(emb, wgt, inv_e, inv_w, labels, flag, dflag, row_sum, lablogit);
    loss_kernel<<<1, 512, 0, stream>>>(row_sum, lablogit, out);
  }
}

// Round 11
// 422.061 us; speedup vs baseline: 1.0990x; 1.0108x over previous
//
#include <hip/hip_runtime.h>
#include <hip/hip_bf16.h>
#include <math.h>

// ---------------- problem constants ----------------
#define B_ROWS 1024
#define EMB    512
#define NCLS   100000
#define SCALE_ 64.0f
// margin = 0.5
#define COS_M 0.8775825618903728f
#define SIN_M 0.479425538604203f
#define TH_C  (-0.8775825618903728f)
#define MM_C  0.2397127693021015f

// ---------------- fallback GEMM tiling (128^2, BK=32) ----------------
#define BM 128
#define BN 128
#define BK 32
#define NTILES 782   // ceil(100000/128)
#define KCHUNKS 16   // 512/32

// ---------------- fast GEMM: 128x256 tile, BK=64, 8 waves, single-buffered ----
#define BK2   64
#define KCH2  8      // 512/64
#define BN2   256
#define NT3   391    // ceil(100000/256)

typedef __attribute__((ext_vector_type(8))) short bf16x8;   // 8 bf16 = 4 VGPRs
typedef __attribute__((ext_vector_type(4))) short s16x4;
typedef __attribute__((ext_vector_type(4))) float f32x4;

typedef __attribute__((address_space(1))) const unsigned int GLP;
typedef __attribute__((address_space(3))) unsigned int LDP;

__device__ __forceinline__ float bf2f(short u) {
  unsigned int x = ((unsigned int)(unsigned short)u) << 16;
  return __builtin_bit_cast(float, x);
}
__device__ __forceinline__ short f2bf(float f) {   // RNE fp32 -> bf16
  unsigned int u = __builtin_bit_cast(unsigned int, f);
  u += 0x7FFF + ((u >> 16) & 1);
  return (short)(u >> 16);
}

// async global->LDS, 16B/lane; LDS dest = wave-uniform base, lane i lands at base + i*16
__device__ __forceinline__ void load16(const void* g, void* l) {
  __builtin_amdgcn_global_load_lds((GLP*)g, (LDP*)l, 16, 0, 0);
}

#define MFMA16 __builtin_amdgcn_mfma_f32_16x16x32_bf16

// ---------------- setup: zero accums, detect label width AND input dtype ----------------
__global__ void setup_kernel(const void* __restrict__ emb, const int* __restrict__ labels,
                             float* __restrict__ row_sum, float* __restrict__ accum,
                             int* __restrict__ flag, int* __restrict__ dflag) {
  const int t = threadIdx.x;           // 512 threads
  row_sum[t] = 0.f;
  row_sum[t + 512] = 0.f;
  if (t == 0) *accum = 0.f;

  // ---- input dtype probe (wave 0): ssq of emb row 0 read AS bf16.
  if (t < 64) {
    bf16x8 v = *(const bf16x8*)((const short*)emb + t * 8);
    float s = 0.f;
    #pragma unroll
    for (int j = 0; j < 8; ++j) { float f = bf2f(v[j]); s += f * f; }
    #pragma unroll
    for (int off = 1; off < 64; off <<= 1) s += __shfl_xor(s, off);
    if (t == 0) *dflag = (s < 1e8f) ? 1 : 0;       // NaN/inf compare false -> fp32
  }

  // ---- label width probe: high words if int64 are all zero
  int v = labels[2 * t + 1];
  #pragma unroll
  for (int off = 1; off < 64; off <<= 1) v |= __shfl_xor(v, off);
  __shared__ int red[8];
  if ((t & 63) == 0) red[t >> 6] = v;
  __syncthreads();
  if (t == 0) {
    int o = 0;
    #pragma unroll
    for (int i = 0; i < 8; ++i) o |= red[i];
    *flag = (o == 0) ? 1 : 0;          // 1 => int64 labels (read low word at 2*r)
  }
}

// ---------------- inverse L2 norms + (optional) normalized-bf16 write-back ----------------
// v4 (proven round 6): 16 lanes/row, 2 rows/thread (16 outstanding loads),
// non-temporal fp32 reads (dead after this pass; keep L3 for the Wn stream).
__global__ __launch_bounds__(256) void normconv_kernel(
    const void* __restrict__ emb, const void* __restrict__ wgt,
    const int* __restrict__ dflag,
    float* __restrict__ inv_e, float* __restrict__ inv_w,
    short* __restrict__ An, short* __restrict__ Wn, const int do_conv) {
  const int sub  = threadIdx.x & 15;       // lane within row-group
  const int rloc = threadIdx.x >> 4;       // 0..15
  const int isbf16 = *dflag;

  const float* pf[2];
  const short* pb[2];
  float* dst[2];
  short* out[2];
  bool   ok[2];
  #pragma unroll
  for (int h = 0; h < 2; ++h) {
    const int row = blockIdx.x * 32 + h * 16 + rloc;
    int r;
    const void* base;
    if (row < B_ROWS) {                      // blocks 0..31 are pure-emb (1024 = 32*32)
      r = row; base = emb; dst[h] = inv_e + row; out[h] = An + (size_t)row * EMB; ok[h] = true;
    } else {
      r = row - B_ROWS;
      ok[h] = (r < NCLS);
      if (r >= NCLS) r = NCLS - 1;           // clamp: safe load, stores guarded
      base = wgt; dst[h] = inv_w + r; out[h] = Wn + (size_t)r * EMB;
    }
    pf[h] = (const float*)base + (size_t)r * EMB;
    pb[h] = (const short*)base + (size_t)r * EMB;
  }

  if (!isbf16) {
    f32x4 v[2][8];
    #pragma unroll
    for (int j = 0; j < 8; ++j) {           // interleave the two rows' streams
      v[0][j] = __builtin_nontemporal_load((const f32x4*)(pf[0] + j * 64 + sub * 4));
      v[1][j] = __builtin_nontemporal_load((const f32x4*)(pf[1] + j * 64 + sub * 4));
    }
    #pragma unroll
    for (int h = 0; h < 2; ++h) {
      float s = 0.f;
      #pragma unroll
      for (int j = 0; j < 8; ++j)
        #pragma unroll
        for (int t = 0; t < 4; ++t) s += v[h][j][t] * v[h][j][t];
      #pragma unroll
      for (int off = 1; off < 16; off <<= 1) s += __shfl_xor(s, off);
      const float inv = 1.f / fmaxf(sqrtf(s), 1e-12f);
      if (ok[h]) {
        if (sub == 0) *dst[h] = inv;
        if (do_conv) {
          #pragma unroll
          for (int j = 0; j < 8; ++j) {
            s16x4 o;
            #pragma unroll
            for (int t = 0; t < 4; ++t) o[t] = f2bf(v[h][j][t] * inv);
            *(s16x4*)(out[h] + j * 64 + sub * 4) = o;
          }
        }
      }
    }
  } else {
    bf16x8 w[2][4];
    #pragma unroll
    for (int j = 0; j < 4; ++j) {
      w[0][j] = *(const bf16x8*)(pb[0] + j * 128 + sub * 8);
      w[1][j] = *(const bf16x8*)(pb[1] + j * 128 + sub * 8);
    }
    #pragma unroll
    for (int h = 0; h < 2; ++h) {
      float s = 0.f;
      #pragma unroll
      for (int j = 0; j < 4; ++j)
        #pragma unroll
        for (int t = 0; t < 8; ++t) { float f = bf2f(w[h][j][t]); s += f * f; }
      #pragma unroll
      for (int off = 1; off < 16; off <<= 1) s += __shfl_xor(s, off);
      const float inv = 1.f / fmaxf(sqrtf(s), 1e-12f);
      if (ok[h]) {
        if (sub == 0) *dst[h] = inv;
        if (do_conv) {
          #pragma unroll
          for (int j = 0; j < 4; ++j) {
            bf16x8 o;
            #pragma unroll
            for (int t = 0; t < 8; ++t) o[t] = f2bf(bf2f(w[h][j][t]) * inv);
            *(bf16x8*)(out[h] + j * 128 + sub * 8) = o;
          }
        }
      }
    }
  }
}

// ---------------- FAST PATH: 128x256 BK=64 NT-GEMM, 8 waves (2M x 4N) ----------------
// Round-10 skeleton widened in N: 256 MFMA per barrier-pair (2x) amortizes the fixed
// per-chunk costs; per-wave tile still 64x64 (same 64-VGPR body). LDS 51.7KB -> 3
// blocks/CU = 24 waves. XCD-grouped mapping; XOR swizzle phys_slot = logical ^ (row&7).
__global__ __launch_bounds__(512, 4) void arc_gemm_fast(
    const short* __restrict__ A, const short* __restrict__ W,
    const int* __restrict__ labels, const int* __restrict__ flag,
    float* __restrict__ row_sum, float* __restrict__ lablogit) {
  // XCD-aware decode: XCD k owns N-panels with ytile%8==k; 8 xtiles per panel.
  const int bid = blockIdx.x;
  const int k   = bid & 7;
  const int j   = bid >> 3;              // 0..391
  const int ytile = (j >> 3) * 8 + k;    // 256-wide N-panel
  const int xtile = j & 7;               // 128-tall M-tile
  if (ytile >= NT3) return;

  __shared__ short As[BM * BK2];    // 16 KB, [row][slot] phys, row stride 128 B
  __shared__ short Bs[BN2 * BK2];   // 32 KB
  __shared__ int   sh_lab[BM];
  __shared__ float sh_sum[BM][4];

  const int tid  = threadIdx.x;
  const int wave = tid >> 6;        // 0..7
  const int lane = tid & 63;
  const int wm = wave >> 2;         // 0..1  (M half: 64 rows)
  const int wn = wave & 3;          // 0..3  (N quarter: 64 cols)
  const int lr = lane & 15;
  const int lk = lane >> 4;
  const int mBase = xtile * BM;
  const int nBase = ytile * BN2;

  // staging: each gload_lds covers 8 rows x 128 B; lane -> row_in=lane>>3, phys=lane&7.
  // source fetches the logical slot that belongs at phys:  sslot = (lane&7) ^ ((lane>>3)&7).
  const int srow8 = lane >> 3;                       // row within 8-row stripe
  const int sslot = (lane & 7) ^ (srow8 & 7);

  f32x4 zero = {0.f, 0.f, 0.f, 0.f};
  f32x4 acc[4][4];
  #pragma unroll
  for (int i = 0; i < 4; ++i)
    #pragma unroll
    for (int jj = 0; jj < 4; ++jj) acc[i][jj] = zero;

  const char* Ab = (const char*)A;   // bf16 row stride 1024 B
  const char* Wb = (const char*)W;

  for (int kc = 0; kc < KCH2; ++kc) {
    __syncthreads();
    const size_t koff = (size_t)kc * 128 + sslot * 16;
    // A: 16 stage-instrs (8 rows each); wave handles {wave, wave+8}
    #pragma unroll
    for (int it = 0; it < 2; ++it) {
      const int i = wave + it * 8;
      const int ar = mBase + i * 8 + srow8;         // always < 1024
      load16(Ab + (size_t)ar * 1024 + koff, (char*)As + (size_t)i * 1024);
    }
    // B: 32 stage-instrs; wave handles {wave, wave+8, wave+16, wave+24}
    #pragma unroll
    for (int it = 0; it < 4; ++it) {
      const int i = wave + it * 8;
      int br = nBase + i * 8 + srow8;
      if (br >= NCLS) br = NCLS - 1;                // clamp; masked in epilogue
      load16(Wb + (size_t)br * 1024 + koff, (char*)Bs + (size_t)i * 1024);
    }
    __syncthreads();                                // drains vmcnt/lgkmcnt before use

    bf16x8 af[2][4], bfr[2][4];
    #pragma unroll
    for (int mi = 0; mi < 4; ++mi) {
      const int ra = wm * 64 + mi * 16 + lr;
      af[0][mi] = *(const bf16x8*)(As + ra * BK2 + ((lk       ^ (ra & 7)) * 8));
      af[1][mi] = *(const bf16x8*)(As + ra * BK2 + (((4 | lk) ^ (ra & 7)) * 8));
    }
    #pragma unroll
    for (int ni = 0; ni < 4; ++ni) {
      const int rb = wn * 64 + ni * 16 + lr;
      bfr[0][ni] = *(const bf16x8*)(Bs + rb * BK2 + ((lk       ^ (rb & 7)) * 8));
      bfr[1][ni] = *(const bf16x8*)(Bs + rb * BK2 + (((4 | lk) ^ (rb & 7)) * 8));
    }
    #pragma unroll
    for (int mi = 0; mi < 4; ++mi)
      #pragma unroll
      for (int ni = 0; ni < 4; ++ni) {
        acc[mi][ni] = MFMA16(af[0][mi], bfr[0][ni], acc[mi][ni], 0, 0, 0);
        acc[mi][ni] = MFMA16(af[1][mi], bfr[1][ni], acc[mi][ni], 0, 0, 0);
      }
  }

  // ---- epilogue (cos = accumulator directly; inputs pre-normalized) ----
  __syncthreads();
  if (tid < BM) {
    const int r = mBase + tid;
    const int f = *flag;
    sh_lab[tid] = labels[f ? (size_t)(2 * r) : (size_t)r];
  }
  __syncthreads();

  #pragma unroll
  for (int mi = 0; mi < 4; ++mi) {
    #pragma unroll
    for (int reg = 0; reg < 4; ++reg) {
      const int lrow = wm * 64 + mi * 16 + lk * 4 + reg;   // C/D: row=(lane>>4)*4+reg
      const int grow = mBase + lrow;
      const int lab = sh_lab[lrow];
      float s = 0.f;
      #pragma unroll
      for (int ni = 0; ni < 4; ++ni) {
        const int gcol = nBase + wn * 64 + ni * 16 + lr;   // C/D: col=lane&15
        if (gcol < NCLS) {
          const float cosv = acc[mi][ni][reg];
          float logit;
          if (gcol == lab) {
            const float sine = sqrtf(fmaxf(1.f - cosv * cosv, 0.f));
            float phi = cosv * COS_M - sine * SIN_M;
            phi = (cosv > TH_C) ? phi : (cosv - MM_C);
            logit = SCALE_ * phi;
            lablogit[grow] = logit;                        // unique writer grid-wide
          } else {
            logit = SCALE_ * cosv;
          }
          s += __expf(logit - SCALE_);                     // offset-64 softmax partial
        }
      }
      #pragma unroll
      for (int off = 1; off < 16; off <<= 1) s += __shfl_xor(s, off);
      if (lr == 0) sh_sum[lrow][wn] = s;
    }
  }
  __syncthreads();
  if (tid < BM)
    atomicAdd(&row_sum[mBase + tid],
              (sh_sum[tid][0] + sh_sum[tid][1]) + (sh_sum[tid][2] + sh_sum[tid][3]));
}

// ---------------- FALLBACK: fused NT-GEMM with in-loop dtype staging (BK=32) ----------------
__global__ __launch_bounds__(256, 3) void arc_gemm(
    const void* __restrict__ A, const void* __restrict__ W,
    const float* __restrict__ inv_e, const float* __restrict__ inv_w,
    const int* __restrict__ labels, const int* __restrict__ flag,
    const int* __restrict__ dflag,
    float* __restrict__ row_sum, float* __restrict__ lablogit) {
  __shared__ short As[BM * BK];
  __shared__ short Bs[BN * BK];
  __shared__ int   sh_lab[BM];
  __shared__ float sh_sum[BM][2];

  const int tid  = threadIdx.x;
  const int wave = tid >> 6;
  const int lane = tid & 63;
  const int wy = wave >> 1;
  const int wx = wave & 1;
  const int lr = lane & 15;
  const int lk = lane >> 4;
  const int mBase = blockIdx.x * BM;
  const int nBase = blockIdx.y * BN;
  const int isbf16 = *dflag;

  const int srow  = lane >> 2;
  const int sbyte = (lane & 3) * 16;

  f32x4 zero = {0.f, 0.f, 0.f, 0.f};
  f32x4 acc[4][4];
  #pragma unroll
  for (int i = 0; i < 4; ++i)
    #pragma unroll
    for (int j = 0; j < 4; ++j) acc[i][j] = zero;

  const char*  Ab = (const char*)A;
  const char*  Wb = (const char*)W;
  const float* Af = (const float*)A;
  const float* Wf = (const float*)W;

  for (int kc = 0; kc < KCHUNKS; ++kc) {
    __syncthreads();
    if (isbf16) {
      const size_t koff = (size_t)kc * 64 + sbyte;
      #pragma unroll
      for (int it = 0; it < 2; ++it) {
        const int c = wave + it * 4;
        const int ar = mBase + c * 16 + srow;
        load16(Ab + (size_t)ar * 1024 + koff, (char*)As + (size_t)c * 1024);
        int br = nBase + c * 16 + srow;
        if (br >= NCLS) br = NCLS - 1;
        load16(Wb + (size_t)br * 1024 + koff, (char*)Bs + (size_t)c * 1024);
      }
    } else {
      #pragma unroll
      for (int p = 0; p < 2; ++p) {
        const int u   = p * 256 + tid;
        const int row = u >> 2;
        const int seg = u & 3;
        const float* ga = Af + ((size_t)(mBase + row) * EMB + kc * 32 + seg * 8);
        f32x4 x = *(const f32x4*)ga;
        f32x4 y = *(const f32x4*)(ga + 4);
        bf16x8 tpack;
        #pragma unroll
        for (int j = 0; j < 4; ++j) { tpack[j] = f2bf(x[j]); tpack[j + 4] = f2bf(y[j]); }
        *(bf16x8*)(As + row * BK + seg * 8) = tpack;
        int br = nBase + row;
        if (br >= NCLS) br = NCLS - 1;
        const float* gb = Wf + ((size_t)br * EMB + kc * 32 + seg * 8);
        x = *(const f32x4*)gb;
        y = *(const f32x4*)(gb + 4);
        #pragma unroll
        for (int j = 0; j < 4; ++j) { tpack[j] = f2bf(x[j]); tpack[j + 4] = f2bf(y[j]); }
        *(bf16x8*)(Bs + row * BK + seg * 8) = tpack;
      }
    }
    __syncthreads();
    bf16x8 af[4], bfr[4];
    #pragma unroll
    for (int mi = 0; mi < 4; ++mi)
      af[mi] = *(const bf16x8*)(As + ((wy * 64 + mi * 16 + lr) * BK + lk * 8));
    #pragma unroll
    for (int ni = 0; ni < 4; ++ni)
      bfr[ni] = *(const bf16x8*)(Bs + ((wx * 64 + ni * 16 + lr) * BK + lk * 8));
    #pragma unroll
    for (int mi = 0; mi < 4; ++mi)
      #pragma unroll
      for (int ni = 0; ni < 4; ++ni)
        acc[mi][ni] = MFMA16(af[mi], bfr[ni], acc[mi][ni], 0, 0, 0);
  }

  __syncthreads();
  if (tid < BM) {
    const int r = mBase + tid;
    const int f = *flag;
    sh_lab[tid] = labels[f ? (size_t)(2 * r) : (size_t)r];
  }
  __syncthreads();

  #pragma unroll
  for (int mi = 0; mi < 4; ++mi) {
    #pragma unroll
    for (int reg = 0; reg < 4; ++reg) {
      const int lrow = wy * 64 + mi * 16 + lk * 4 + reg;
      const int grow = mBase + lrow;
      const float ie = inv_e[grow];
      const int lab = sh_lab[lrow];
      float s = 0.f;
      #pragma unroll
      for (int ni = 0; ni < 4; ++ni) {
        const int gcol = nBase + wx * 64 + ni * 16 + lr;
        if (gcol < NCLS) {
          const float cosv = acc[mi][ni][reg] * ie * inv_w[gcol];
          float logit;
          if (gcol == lab) {
            const float sine = sqrtf(fmaxf(1.f - cosv * cosv, 0.f));
            float phi = cosv * COS_M - sine * SIN_M;
            phi = (cosv > TH_C) ? phi : (cosv - MM_C);
            logit = SCALE_ * phi;
            lablogit[grow] = logit;
          } else {
            logit = SCALE_ * cosv;
          }
          s += __expf(logit - SCALE_);
        }
      }
      #pragma unroll
      for (int off = 1; off < 16; off <<= 1) s += __shfl_xor(s, off);
      if (lr == 0) sh_sum[lrow][wx] = s;
    }
  }
  __syncthreads();
  if (tid < BM)
    atomicAdd(&row_sum[mBase + tid], sh_sum[tid][0] + sh_sum[tid][1]);
}

// ---------------- fused per-row loss -> mean (single block) ----------------
__global__ __launch_bounds__(512) void loss_kernel(const float* __restrict__ row_sum,
                                                   const float* __restrict__ lablogit,
                                                   float* __restrict__ out) {
  const int t = threadIdx.x;
  float loss = 0.f;
  #pragma unroll
  for (int i = 0; i < 2; ++i) {
    const int r = t + i * 512;
    loss += SCALE_ + logf(row_sum[r]) - lablogit[r];
  }
  #pragma unroll
  for (int off = 1; off < 64; off <<= 1) loss += __shfl_xor(loss, off);
  __shared__ float rs[8];
  if ((t & 63) == 0) rs[t >> 6] = loss;
  __syncthreads();
  if (t == 0) {
    float s = 0.f;
    #pragma unroll
    for (int i = 0; i < 8; ++i) s += rs[i];
    out[0] = s * (1.0f / 1024.0f);   // reference output is float32
  }
}

// ---------------- launch ----------------
extern "C" void kernel_launch(void* const* d_in, const int* in_sizes, int n_in,
                              void* d_out, int out_size, void* d_ws, size_t ws_size,
                              hipStream_t stream) {
  const void* emb   = d_in[0];          // [1024][512]  bf16 or fp32 (auto-detected)
  const void* wgt   = d_in[1];          // [100000][512]
  const int* labels = (const int*)d_in[2];   // int32 or int64 (auto-detected)
  float* out = (float*)d_out;

  const int NORM_BLOCKS = (B_ROWS + NCLS + 31) / 32;   // 32 rows/block, 2 rows/thread

  // fast-path workspace: pre-normalized bf16 copies of W and A
  const size_t WN_SHORTS = (size_t)NCLS * EMB;        // 51,200,000
  const size_t AN_SHORTS = (size_t)B_ROWS * EMB;      // 524,288
  const size_t FAST_NEED = (WN_SHORTS + AN_SHORTS) * 2 + 103075u * 4;  // ~103.9 MB

  if (ws_size >= FAST_NEED) {
    short* Wn = (short*)d_ws;
    short* An = Wn + WN_SHORTS;
    float* tail     = (float*)(An + AN_SHORTS);
    float* inv_e    = tail;               // 1024 (fallback parity)
    float* inv_w    = tail + 1024;        // 100000
    float* lablogit = tail + 101024;      // 1024
    float* row_sum  = tail + 102048;      // 1024
    float* accum    = tail + 103072;      // 1
    int*   flag     = (int*)(tail + 103073);
    int*   dflag    = (int*)(tail + 103074);

    setup_kernel<<<1, 512, 0, stream>>>(emb, labels, row_sum, accum, flag, dflag);
    normconv_kernel<<<NORM_BLOCKS, 256, 0, stream>>>(
        emb, wgt, dflag, inv_e, inv_w, An, Wn, 1);
    // 8 XCDs x 392 blocks each (49 y-groups x 8 x-tiles); 8 no-op blocks
    arc_gemm_fast<<<8 * 392, 512, 0, stream>>>(An, Wn, labels, flag, row_sum, lablogit);
    loss_kernel<<<1, 512, 0, stream>>>(row_sum, lablogit, out);
  } else {
    float* ws       = (float*)d_ws;
    float* inv_e    = ws;                 // 1024
    float* inv_w    = ws + 1024;          // 100000
    float* lablogit = ws + 101024;        // 1024
    float* row_sum  = ws + 102048;        // 1024
    float* accum    = ws + 103072;        // 1
    int*   flag     = (int*)(ws + 103073);
    int*   dflag    = (int*)(ws + 103074);

    setup_kernel<<<1, 512, 0, stream>>>(emb, labels, row_sum, accum, flag, dflag);
    normconv_kernel<<<NORM_BLOCKS, 256, 0, stream>>>(
        emb, wgt, dflag, inv_e, inv_w, (short*)inv_e, (short*)inv_e, 0);
    dim3 grid(8, NTILES);
    arc_gemm<<<grid, 256, 0, stream>>>(emb, wgt, inv_e, inv_w, labels, flag, dflag, row_sum, lablogit);
    loss_kernel<<<1, 512, 0, stream>>>(row_sum, lablogit, out);
  }
}

// Round 13
// 413.099 us; speedup vs baseline: 1.1228x; 1.0217x over previous
//
#include <hip/hip_runtime.h>
#include <hip/hip_bf16.h>
#include <math.h>

// ---------------- problem constants ----------------
#define B_ROWS 1024
#define EMB    512
#define NCLS   100000
#define SCALE_ 64.0f
// margin = 0.5
#define COS_M 0.8775825618903728f
#define SIN_M 0.479425538604203f
#define TH_C  (-0.8775825618903728f)
#define MM_C  0.2397127693021015f

// ---------------- fallback GEMM tiling (128^2, BK=32) ----------------
#define BM 128
#define BN 128
#define BK 32
#define NTILES 782   // ceil(100000/128)
#define KCHUNKS 16   // 512/32

// ---------------- fast GEMM: 128x256 tile, BK=64, 8 waves, single-buffered ----
#define BK2   64
#define KCH2  8      // 512/64
#define BN2   256
#define NT3   391    // ceil(100000/256)

typedef __attribute__((ext_vector_type(8))) short bf16x8;   // 8 bf16 = 4 VGPRs
typedef __attribute__((ext_vector_type(4))) short s16x4;
typedef __attribute__((ext_vector_type(4))) float f32x4;
typedef __attribute__((ext_vector_type(2))) unsigned int u32x2;

typedef __attribute__((address_space(1))) const unsigned int GLP;
typedef __attribute__((address_space(3))) unsigned int LDP;

__device__ __forceinline__ float bf2f(short u) {
  unsigned int x = ((unsigned int)(unsigned short)u) << 16;
  return __builtin_bit_cast(float, x);
}
__device__ __forceinline__ short f2bf(float f) {   // RNE fp32 -> bf16 (manual)
  unsigned int u = __builtin_bit_cast(unsigned int, f);
  u += 0x7FFF + ((u >> 16) & 1);
  return (short)(u >> 16);
}
// compiler-paired RNE conversion: emits v_cvt_pk_bf16_f32 (1 op / 2 elems),
// bit-identical to f2bf for finite inputs. memcpy (not bit_cast): __hip_bfloat162
// is not trivially copyable in these headers; memcpy folds to a register move.
__device__ __forceinline__ unsigned int pk2bf(float a, float b) {
  __hip_bfloat162 h = __float22bfloat162_rn(make_float2(a, b));
  unsigned int r;
  __builtin_memcpy(&r, &h, 4);
  return r;
}

// async global->LDS, 16B/lane; LDS dest = wave-uniform base, lane i lands at base + i*16
__device__ __forceinline__ void load16(const void* g, void* l) {
  __builtin_amdgcn_global_load_lds((GLP*)g, (LDP*)l, 16, 0, 0);
}

#define MFMA16 __builtin_amdgcn_mfma_f32_16x16x32_bf16

// ---------------- setup: zero accums, detect label width AND input dtype ----------------
__global__ void setup_kernel(const void* __restrict__ emb, const int* __restrict__ labels,
                             float* __restrict__ row_sum, float* __restrict__ accum,
                             int* __restrict__ flag, int* __restrict__ dflag) {
  const int t = threadIdx.x;           // 512 threads
  row_sum[t] = 0.f;
  row_sum[t + 512] = 0.f;
  if (t == 0) *accum = 0.f;

  // ---- input dtype probe (wave 0): ssq of emb row 0 read AS bf16.
  if (t < 64) {
    bf16x8 v = *(const bf16x8*)((const short*)emb + t * 8);
    float s = 0.f;
    #pragma unroll
    for (int j = 0; j < 8; ++j) { float f = bf2f(v[j]); s += f * f; }
    #pragma unroll
    for (int off = 1; off < 64; off <<= 1) s += __shfl_xor(s, off);
    if (t == 0) *dflag = (s < 1e8f) ? 1 : 0;       // NaN/inf compare false -> fp32
  }

  // ---- label width probe: high words if int64 are all zero
  int v = labels[2 * t + 1];
  #pragma unroll
  for (int off = 1; off < 64; off <<= 1) v |= __shfl_xor(v, off);
  __shared__ int red[8];
  if ((t & 63) == 0) red[t >> 6] = v;
  __syncthreads();
  if (t == 0) {
    int o = 0;
    #pragma unroll
    for (int i = 0; i < 8; ++i) o |= red[i];
    *flag = (o == 0) ? 1 : 0;          // 1 => int64 labels (read low word at 2*r)
  }
}

// ---------------- inverse L2 norms + (optional) normalized-bf16 write-back ----------------
// v5: v4 structure (16 lanes/row, 2 rows/thread, non-temporal fp32 reads) with the
// store-conversion switched to compiler-paired v_cvt_pk_bf16_f32 (T12/m240: the
// compiler's cast path beats hand-written RNE bit-twiddling; ~6x fewer VALU ops).
__global__ __launch_bounds__(256) void normconv_kernel(
    const void* __restrict__ emb, const void* __restrict__ wgt,
    const int* __restrict__ dflag,
    float* __restrict__ inv_e, float* __restrict__ inv_w,
    short* __restrict__ An, short* __restrict__ Wn, const int do_conv) {
  const int sub  = threadIdx.x & 15;       // lane within row-group
  const int rloc = threadIdx.x >> 4;       // 0..15
  const int isbf16 = *dflag;

  const float* pf[2];
  const short* pb[2];
  float* dst[2];
  short* out[2];
  bool   ok[2];
  #pragma unroll
  for (int h = 0; h < 2; ++h) {
    const int row = blockIdx.x * 32 + h * 16 + rloc;
    int r;
    const void* base;
    if (row < B_ROWS) {                      // blocks 0..31 are pure-emb (1024 = 32*32)
      r = row; base = emb; dst[h] = inv_e + row; out[h] = An + (size_t)row * EMB; ok[h] = true;
    } else {
      r = row - B_ROWS;
      ok[h] = (r < NCLS);
      if (r >= NCLS) r = NCLS - 1;           // clamp: safe load, stores guarded
      base = wgt; dst[h] = inv_w + r; out[h] = Wn + (size_t)r * EMB;
    }
    pf[h] = (const float*)base + (size_t)r * EMB;
    pb[h] = (const short*)base + (size_t)r * EMB;
  }

  if (!isbf16) {
    f32x4 v[2][8];
    #pragma unroll
    for (int j = 0; j < 8; ++j) {           // interleave the two rows' streams
      v[0][j] = __builtin_nontemporal_load((const f32x4*)(pf[0] + j * 64 + sub * 4));
      v[1][j] = __builtin_nontemporal_load((const f32x4*)(pf[1] + j * 64 + sub * 4));
    }
    #pragma unroll
    for (int h = 0; h < 2; ++h) {
      float s = 0.f;
      #pragma unroll
      for (int j = 0; j < 8; ++j)
        #pragma unroll
        for (int t = 0; t < 4; ++t) s += v[h][j][t] * v[h][j][t];
      #pragma unroll
      for (int off = 1; off < 16; off <<= 1) s += __shfl_xor(s, off);
      const float inv = 1.f / fmaxf(sqrtf(s), 1e-12f);
      if (ok[h]) {
        if (sub == 0) *dst[h] = inv;
        if (do_conv) {
          #pragma unroll
          for (int j = 0; j < 8; ++j) {
            u32x2 o;
            o[0] = pk2bf(v[h][j][0] * inv, v[h][j][1] * inv);
            o[1] = pk2bf(v[h][j][2] * inv, v[h][j][3] * inv);
            *(u32x2*)(out[h] + j * 64 + sub * 4) = o;
          }
        }
      }
    }
  } else {
    bf16x8 w[2][4];
    #pragma unroll
    for (int j = 0; j < 4; ++j) {
      w[0][j] = *(const bf16x8*)(pb[0] + j * 128 + sub * 8);
      w[1][j] = *(const bf16x8*)(pb[1] + j * 128 + sub * 8);
    }
    #pragma unroll
    for (int h = 0; h < 2; ++h) {
      float s = 0.f;
      #pragma unroll
      for (int j = 0; j < 4; ++j)
        #pragma unroll
        for (int t = 0; t < 8; ++t) { float f = bf2f(w[h][j][t]); s += f * f; }
      #pragma unroll
      for (int off = 1; off < 16; off <<= 1) s += __shfl_xor(s, off);
      const float inv = 1.f / fmaxf(sqrtf(s), 1e-12f);
      if (ok[h]) {
        if (sub == 0) *dst[h] = inv;
        if (do_conv) {
          #pragma unroll
          for (int j = 0; j < 4; ++j) {
            u32x2 o0;
            o0[0] = pk2bf(bf2f(w[h][j][0]) * inv, bf2f(w[h][j][1]) * inv);
            o0[1] = pk2bf(bf2f(w[h][j][2]) * inv, bf2f(w[h][j][3]) * inv);
            u32x2 o1;
            o1[0] = pk2bf(bf2f(w[h][j][4]) * inv, bf2f(w[h][j][5]) * inv);
            o1[1] = pk2bf(bf2f(w[h][j][6]) * inv, bf2f(w[h][j][7]) * inv);
            *(u32x2*)(out[h] + j * 128 + sub * 8) = o0;
            *(u32x2*)(out[h] + j * 128 + sub * 8 + 4) = o1;
          }
        }
      }
    }
  }
}

// ---------------- FAST PATH: 128x256 BK=64 NT-GEMM, 8 waves (2M x 4N) ----------------
// (round-11 proven, FROZEN: 141.6 us, MfmaUtil 32%, conflicts 0, VGPR 64)
__global__ __launch_bounds__(512, 4) void arc_gemm_fast(
    const short* __restrict__ A, const short* __restrict__ W,
    const int* __restrict__ labels, const int* __restrict__ flag,
    float* __restrict__ row_sum, float* __restrict__ lablogit) {
  // XCD-aware decode: XCD k owns N-panels with ytile%8==k; 8 xtiles per panel.
  const int bid = blockIdx.x;
  const int k   = bid & 7;
  const int j   = bid >> 3;              // 0..391
  const int ytile = (j >> 3) * 8 + k;    // 256-wide N-panel
  const int xtile = j & 7;               // 128-tall M-tile
  if (ytile >= NT3) return;

  __shared__ short As[BM * BK2];    // 16 KB, [row][slot] phys, row stride 128 B
  __shared__ short Bs[BN2 * BK2];   // 32 KB
  __shared__ int   sh_lab[BM];
  __shared__ float sh_sum[BM][4];

  const int tid  = threadIdx.x;
  const int wave = tid >> 6;        // 0..7
  const int lane = tid & 63;
  const int wm = wave >> 2;         // 0..1  (M half: 64 rows)
  const int wn = wave & 3;          // 0..3  (N quarter: 64 cols)
  const int lr = lane & 15;
  const int lk = lane >> 4;
  const int mBase = xtile * BM;
  const int nBase = ytile * BN2;

  // staging: each gload_lds covers 8 rows x 128 B; lane -> row_in=lane>>3, phys=lane&7.
  // source fetches the logical slot that belongs at phys:  sslot = (lane&7) ^ ((lane>>3)&7).
  const int srow8 = lane >> 3;                       // row within 8-row stripe
  const int sslot = (lane & 7) ^ (srow8 & 7);

  f32x4 zero = {0.f, 0.f, 0.f, 0.f};
  f32x4 acc[4][4];
  #pragma unroll
  for (int i = 0; i < 4; ++i)
    #pragma unroll
    for (int jj = 0; jj < 4; ++jj) acc[i][jj] = zero;

  const char* Ab = (const char*)A;   // bf16 row stride 1024 B
  const char* Wb = (const char*)W;

  for (int kc = 0; kc < KCH2; ++kc) {
    __syncthreads();
    const size_t koff = (size_t)kc * 128 + sslot * 16;
    // A: 16 stage-instrs (8 rows each); wave handles {wave, wave+8}
    #pragma unroll
    for (int it = 0; it < 2; ++it) {
      const int i = wave + it * 8;
      const int ar = mBase + i * 8 + srow8;         // always < 1024
      load16(Ab + (size_t)ar * 1024 + koff, (char*)As + (size_t)i * 1024);
    }
    // B: 32 stage-instrs; wave handles {wave, wave+8, wave+16, wave+24}
    #pragma unroll
    for (int it = 0; it < 4; ++it) {
      const int i = wave + it * 8;
      int br = nBase + i * 8 + srow8;
      if (br >= NCLS) br = NCLS - 1;                // clamp; masked in epilogue
      load16(Wb + (size_t)br * 1024 + koff, (char*)Bs + (size_t)i * 1024);
    }
    __syncthreads();                                // drains vmcnt/lgkmcnt before use

    bf16x8 af[2][4], bfr[2][4];
    #pragma unroll
    for (int mi = 0; mi < 4; ++mi) {
      const int ra = wm * 64 + mi * 16 + lr;
      af[0][mi] = *(const bf16x8*)(As + ra * BK2 + ((lk       ^ (ra & 7)) * 8));
      af[1][mi] = *(const bf16x8*)(As + ra * BK2 + (((4 | lk) ^ (ra & 7)) * 8));
    }
    #pragma unroll
    for (int ni = 0; ni < 4; ++ni) {
      const int rb = wn * 64 + ni * 16 + lr;
      bfr[0][ni] = *(const bf16x8*)(Bs + rb * BK2 + ((lk       ^ (rb & 7)) * 8));
      bfr[1][ni] = *(const bf16x8*)(Bs + rb * BK2 + (((4 | lk) ^ (rb & 7)) * 8));
    }
    #pragma unroll
    for (int mi = 0; mi < 4; ++mi)
      #pragma unroll
      for (int ni = 0; ni < 4; ++ni) {
        acc[mi][ni] = MFMA16(af[0][mi], bfr[0][ni], acc[mi][ni], 0, 0, 0);
        acc[mi][ni] = MFMA16(af[1][mi], bfr[1][ni], acc[mi][ni], 0, 0, 0);
      }
  }

  // ---- epilogue (cos = accumulator directly; inputs pre-normalized) ----
  __syncthreads();
  if (tid < BM) {
    const int r = mBase + tid;
    const int f = *flag;
    sh_lab[tid] = labels[f ? (size_t)(2 * r) : (size_t)r];
  }
  __syncthreads();

  #pragma unroll
  for (int mi = 0; mi < 4; ++mi) {
    #pragma unroll
    for (int reg = 0; reg < 4; ++reg) {
      const int lrow = wm * 64 + mi * 16 + lk * 4 + reg;   // C/D: row=(lane>>4)*4+reg
      const int grow = mBase + lrow;
      const int lab = sh_lab[lrow];
      float s = 0.f;
      #pragma unroll
      for (int ni = 0; ni < 4; ++ni) {
        const int gcol = nBase + wn * 64 + ni * 16 + lr;   // C/D: col=lane&15
        if (gcol < NCLS) {
          const float cosv = acc[mi][ni][reg];
          float logit;
          if (gcol == lab) {
            const float sine = sqrtf(fmaxf(1.f - cosv * cosv, 0.f));
            float phi = cosv * COS_M - sine * SIN_M;
            phi = (cosv > TH_C) ? phi : (cosv - MM_C);
            logit = SCALE_ * phi;
            lablogit[grow] = logit;                        // unique writer grid-wide
          } else {
            logit = SCALE_ * cosv;
          }
          s += __expf(logit - SCALE_);                     // offset-64 softmax partial
        }
      }
      #pragma unroll
      for (int off = 1; off < 16; off <<= 1) s += __shfl_xor(s, off);
      if (lr == 0) sh_sum[lrow][wn] = s;
    }
  }
  __syncthreads();
  if (tid < BM)
    atomicAdd(&row_sum[mBase + tid],
              (sh_sum[tid][0] + sh_sum[tid][1]) + (sh_sum[tid][2] + sh_sum[tid][3]));
}

// ---------------- FALLBACK: fused NT-GEMM with in-loop dtype staging (BK=32) ----------------
__global__ __launch_bounds__(256, 3) void arc_gemm(
    const void* __restrict__ A, const void* __restrict__ W,
    const float* __restrict__ inv_e, const float* __restrict__ inv_w,
    const int* __restrict__ labels, const int* __restrict__ flag,
    const int* __restrict__ dflag,
    float* __restrict__ row_sum, float* __restrict__ lablogit) {
  __shared__ short As[BM * BK];
  __shared__ short Bs[BN * BK];
  __shared__ int   sh_lab[BM];
  __shared__ float sh_sum[BM][2];

  const int tid  = threadIdx.x;
  const int wave = tid >> 6;
  const int lane = tid & 63;
  const int wy = wave >> 1;
  const int wx = wave & 1;
  const int lr = lane & 15;
  const int lk = lane >> 4;
  const int mBase = blockIdx.x * BM;
  const int nBase = blockIdx.y * BN;
  const int isbf16 = *dflag;

  const int srow  = lane >> 2;
  const int sbyte = (lane & 3) * 16;

  f32x4 zero = {0.f, 0.f, 0.f, 0.f};
  f32x4 acc[4][4];
  #pragma unroll
  for (int i = 0; i < 4; ++i)
    #pragma unroll
    for (int j = 0; j < 4; ++j) acc[i][j] = zero;

  const char*  Ab = (const char*)A;
  const char*  Wb = (const char*)W;
  const float* Af = (const float*)A;
  const float* Wf = (const float*)W;

  for (int kc = 0; kc < KCHUNKS; ++kc) {
    __syncthreads();
    if (isbf16) {
      const size_t koff = (size_t)kc * 64 + sbyte;
      #pragma unroll
      for (int it = 0; it < 2; ++it) {
        const int c = wave + it * 4;
        const int ar = mBase + c * 16 + srow;
        load16(Ab + (size_t)ar * 1024 + koff, (char*)As + (size_t)c * 1024);
        int br = nBase + c * 16 + srow;
        if (br >= NCLS) br = NCLS - 1;
        load16(Wb + (size_t)br * 1024 + koff, (char*)Bs + (size_t)c * 1024);
      }
    } else {
      #pragma unroll
      for (int p = 0; p < 2; ++p) {
        const int u   = p * 256 + tid;
        const int row = u >> 2;
        const int seg = u & 3;
        const float* ga = Af + ((size_t)(mBase + row) * EMB + kc * 32 + seg * 8);
        f32x4 x = *(const f32x4*)ga;
        f32x4 y = *(const f32x4*)(ga + 4);
        bf16x8 tpack;
        #pragma unroll
        for (int j = 0; j < 4; ++j) { tpack[j] = f2bf(x[j]); tpack[j + 4] = f2bf(y[j]); }
        *(bf16x8*)(As + row * BK + seg * 8) = tpack;
        int br = nBase + row;
        if (br >= NCLS) br = NCLS - 1;
        const float* gb = Wf + ((size_t)br * EMB + kc * 32 + seg * 8);
        x = *(const f32x4*)gb;
        y = *(const f32x4*)(gb + 4);
        #pragma unroll
        for (int j = 0; j < 4; ++j) { tpack[j] = f2bf(x[j]); tpack[j + 4] = f2bf(y[j]); }
        *(bf16x8*)(Bs + row * BK + seg * 8) = tpack;
      }
    }
    __syncthreads();
    bf16x8 af[4], bfr[4];
    #pragma unroll
    for (int mi = 0; mi < 4; ++mi)
      af[mi] = *(const bf16x8*)(As + ((wy * 64 + mi * 16 + lr) * BK + lk * 8));
    #pragma unroll
    for (int ni = 0; ni < 4; ++ni)
      bfr[ni] = *(const bf16x8*)(Bs + ((wx * 64 + ni * 16 + lr) * BK + lk * 8));
    #pragma unroll
    for (int mi = 0; mi < 4; ++mi)
      #pragma unroll
      for (int ni = 0; ni < 4; ++ni)
        acc[mi][ni] = MFMA16(af[mi], bfr[ni], acc[mi][ni], 0, 0, 0);
  }

  __syncthreads();
  if (tid < BM) {
    const int r = mBase + tid;
    const int f = *flag;
    sh_lab[tid] = labels[f ? (size_t)(2 * r) : (size_t)r];
  }
  __syncthreads();

  #pragma unroll
  for (int mi = 0; mi < 4; ++mi) {
    #pragma unroll
    for (int reg = 0; reg < 4; ++reg) {
      const int lrow = wy * 64 + mi * 16 + lk * 4 + reg;
      const int grow = mBase + lrow;
      const float ie = inv_e[grow];
      const int lab = sh_lab[lrow];
      float s = 0.f;
      #pragma unroll
      for (int ni = 0; ni < 4; ++ni) {
        const int gcol = nBase + wx * 64 + ni * 16 + lr;
        if (gcol < NCLS) {
          const float cosv = acc[mi][ni][reg] * ie * inv_w[gcol];
          float logit;
          if (gcol == lab) {
            const float sine = sqrtf(fmaxf(1.f - cosv * cosv, 0.f));
            float phi = cosv * COS_M - sine * SIN_M;
            phi = (cosv > TH_C) ? phi : (cosv - MM_C);
            logit = SCALE_ * phi;
            lablogit[grow] = logit;
          } else {
            logit = SCALE_ * cosv;
          }
          s += __expf(logit - SCALE_);
        }
      }
      #pragma unroll
      for (int off = 1; off < 16; off <<= 1) s += __shfl_xor(s, off);
      if (lr == 0) sh_sum[lrow][wx] = s;
    }
  }
  __syncthreads();
  if (tid < BM)
    atomicAdd(&row_sum[mBase + tid], sh_sum[tid][0] + sh_sum[tid][1]);
}

// ---------------- fused per-row loss -> mean (single block) ----------------
__global__ __launch_bounds__(512) void loss_kernel(const float* __restrict__ row_sum,
                                                   const float* __restrict__ lablogit,
                                                   float* __restrict__ out) {
  const int t = threadIdx.x;
  float loss = 0.f;
  #pragma unroll
  for (int i = 0; i < 2; ++i) {
    const int r = t + i * 512;
    loss += SCALE_ + logf(row_sum[r]) - lablogit[r];
  }
  #pragma unroll
  for (int off = 1; off < 64; off <<= 1) loss += __shfl_xor(loss, off);
  __shared__ float rs[8];
  if ((t & 63) == 0) rs[t >> 6] = loss;
  __syncthreads();
  if (t == 0) {
    float s = 0.f;
    #pragma unroll
    for (int i = 0; i < 8; ++i) s += rs[i];
    out[0] = s * (1.0f / 1024.0f);   // reference output is float32
  }
}

// ---------------- launch ----------------
extern "C" void kernel_launch(void* const* d_in, const int* in_sizes, int n_in,
                              void* d_out, int out_size, void* d_ws, size_t ws_size,
                              hipStream_t stream) {
  const void* emb   = d_in[0];          // [1024][512]  bf16 or fp32 (auto-detected)
  const void* wgt   = d_in[1];          // [100000][512]
  const int* labels = (const int*)d_in[2];   // int32 or int64 (auto-detected)
  float* out = (float*)d_out;

  const int NORM_BLOCKS = (B_ROWS + NCLS + 31) / 32;   // 32 rows/block, 2 rows/thread

  // fast-path workspace: pre-normalized bf16 copies of W and A
  const size_t WN_SHORTS = (size_t)NCLS * EMB;        // 51,200,000
  const size_t AN_SHORTS = (size_t)B_ROWS * EMB;      // 524,288
  const size_t FAST_NEED = (WN_SHORTS + AN_SHORTS) * 2 + 103075u * 4;  // ~103.9 MB

  if (ws_size >= FAST_NEED) {
    short* Wn = (short*)d_ws;
    short* An = Wn + WN_SHORTS;
    float* tail     = (float*)(An + AN_SHORTS);
    float* inv_e    = tail;               // 1024 (fallback parity)
    float* inv_w    = tail + 1024;        // 100000
    float* lablogit = tail + 101024;      // 1024
    float* row_sum  = tail + 102048;      // 1024
    float* accum    = tail + 103072;      // 1
    int*   flag     = (int*)(tail + 103073);
    int*   dflag    = (int*)(tail + 103074);

    setup_kernel<<<1, 512, 0, stream>>>(emb, labels, row_sum, accum, flag, dflag);
    normconv_kernel<<<NORM_BLOCKS, 256, 0, stream>>>(
        emb, wgt, dflag, inv_e, inv_w, An, Wn, 1);
    // 8 XCDs x 392 blocks each (49 y-groups x 8 x-tiles); 8 no-op blocks
    arc_gemm_fast<<<8 * 392, 512, 0, stream>>>(An, Wn, labels, flag, row_sum, lablogit);
    loss_kernel<<<1, 512, 0, stream>>>(row_sum, lablogit, out);
  } else {
    float* ws       = (float*)d_ws;
    float* inv_e    = ws;                 // 1024
    float* inv_w    = ws + 1024;          // 100000
    float* lablogit = ws + 101024;        // 1024
    float* row_sum  = ws + 102048;        // 1024
    float* accum    = ws + 103072;        // 1
    int*   flag     = (int*)(ws + 103073);
    int*   dflag    = (int*)(ws + 103074);

    setup_kernel<<<1, 512, 0, stream>>>(emb, labels, row_sum, accum, flag, dflag);
    normconv_kernel<<<NORM_BLOCKS, 256, 0, stream>>>(
        emb, wgt, dflag, inv_e, inv_w, (short*)inv_e, (short*)inv_e, 0);
    dim3 grid(8, NTILES);
    arc_gemm<<<grid, 256, 0, stream>>>(emb, wgt, inv_e, inv_w, labels, flag, dflag, row_sum, lablogit);
    loss_kernel<<<1, 512, 0, stream>>>(row_sum, lablogit, out);
  }
}